// Round 13
// baseline (118.562 us; speedup 1.0000x reference)
//
#include <hip/hip_runtime.h>
#include <hip/hip_fp16.h>
#include <stdint.h>

// GAT: N=4096, F=512, H=8, D=64.
// score(h,i,j) = leaky(es_i + en_j); exp(leaky-M) = max(c1*u, c2*v) with
//   u=exp(en), v=exp(0.2*en), c1=exp(es-M), c2=exp(0.2*es-M); mask = AND with
//   bit-packed A; fixed per-row M => no softmax state, j-partials additive.
//
// attn: block = 32 rows x 1 head = 4 waves (2 rh x 2 jq), grid 1024, ~5 blk/CU.
// Per step each jq stages a 64-j V tile via linear global_load_lds (Vt
// pre-tiled [cc][d][8]), double-buffered. Loop uses RAW s_barrier + counted
// s_waitcnt vmcnt(5) (stage loads wait, scalar prefetches stay in flight) --
// never vmcnt(0) inside the loop. Bits in block-major layout (coalesced).

#define NODES 4096
#define FEAT  512
#define HEADS 8
#define DH    64
#define NT    (NODES / 64)

using half2v = __attribute__((ext_vector_type(2))) _Float16;
using half8  = __attribute__((ext_vector_type(8))) _Float16;
using f32x4  = __attribute__((ext_vector_type(4))) float;

__device__ __forceinline__ void gll16(const void* g, void* l) {
    __builtin_amdgcn_global_load_lds(
        (const __attribute__((address_space(1))) uint32_t*)g,
        (__attribute__((address_space(3))) uint32_t*)l, 16, 0, 0);
}

__device__ __forceinline__ uint32_t fenc(float f) {
    uint32_t u = __float_as_uint(f);
    return (u >> 31) ? ~u : (u | 0x80000000u);
}
__device__ __forceinline__ float fdec(uint32_t e) {
    uint32_t u = (e >> 31) ? (e & 0x7FFFFFFFu) : ~e;
    return __uint_as_float(u);
}

// ---------------- prep: A->bits (streaming rows) | W->WT | enmax=0 ----------------
// Abits2 layout: [iblk 0..127][wc 0..63][row&31]  (u64)
#define PACK_BLOCKS 1024
#define WT_BLOCKS   (HEADS * 8)                // 64

__global__ __launch_bounds__(256) void prep_kernel(
    const float* __restrict__ A, const float* __restrict__ W,
    uint64_t* __restrict__ Abits2, _Float16* __restrict__ WT,
    uint32_t* __restrict__ enmax_u) {
    __shared__ float t[64][65];
    const int bx = blockIdx.x;
    if (bx < PACK_BLOCKS) {
        if (bx == 0 && threadIdx.x < 16) enmax_u[threadIdx.x] = 0;
        const int w    = threadIdx.x >> 6;
        const int lane = threadIdx.x & 63;
        const int row  = bx * 4 + w;
        const float* ar = A + (size_t)row * NODES + lane;
        uint64_t* dst = Abits2 + (size_t)(row >> 5) * 2048 + (row & 31);
        for (int wc = 0; wc < 64; ++wc) {
            uint64_t m = __ballot(ar[wc * 64] != 0.0f);
            if (lane == 0) dst[wc * 32] = m;
        }
        return;
    }
    // W[h][f][d] -> WT[h][d][f] via LDS tile
    const int b2 = bx - PACK_BLOCKS;
    const int h  = b2 >> 3;
    const int ft = b2 & 7;
    const int r  = threadIdx.x >> 6;
    const int c  = threadIdx.x & 63;
#pragma unroll
    for (int r0 = 0; r0 < 64; r0 += 4)
        t[r0 + r][c] = W[((size_t)h * FEAT + ft * 64 + r0 + r) * DH + c];
    __syncthreads();
#pragma unroll
    for (int r0 = 0; r0 < 64; r0 += 4)
        WT[((size_t)h * DH + r0 + r) * FEAT + ft * 64 + c] = (_Float16)t[c][r0 + r];
}

// ---------------- feats: grid (64 n-tiles, 8 heads), 512 thr = 8 waves ----------------
// wave w: n-sub ns=w&3 (16 rows), k-half kh=w>>2 (8 of 16 k-steps). Reads X
// fp32 directly (no cast kernel). LDS combine, kh=0 does epilogue.
// Vt written PRE-TILED per (h,jt): [cc 0..7][d 0..63][e 0..7], j = jt*64+cc*8+e.
__global__ __launch_bounds__(512) void feats_kernel(
    const float* __restrict__ X, const _Float16* __restrict__ WT,
    const float* __restrict__ a_self, const float* __restrict__ a_neigh,
    _Float16* __restrict__ Vt, float* __restrict__ e_self,
    _Float16* __restrict__ u_tab, _Float16* __restrict__ v_tab,
    uint32_t* __restrict__ enmax_u) {
    __shared__ float cmb[4][64][17];
    const int h    = blockIdx.y;
    const int bx   = blockIdx.x;
    const int tid  = threadIdx.x;
    const int w    = tid >> 6;
    const int lane = tid & 63;
    const int l15  = lane & 15;
    const int g    = lane >> 4;
    const int ns   = w & 3;
    const int kh   = w >> 2;
    const int n0   = bx * 64 + ns * 16;

    f32x4 acc[4] = {};
    const float* xb = X + (size_t)(n0 + l15) * FEAT + g * 8;
    const _Float16* wb = WT + (h * DH + l15) * FEAT + g * 8;

#pragma unroll
    for (int kk = 0; kk < 8; ++kk) {
        const int k = (kh * 8 + kk) * 32;
        f32x4 x0 = *(const f32x4*)(xb + k);
        f32x4 x1 = *(const f32x4*)(xb + k + 4);
        half8 b;
#pragma unroll
        for (int e = 0; e < 4; ++e) { b[e] = (_Float16)x0[e]; b[e + 4] = (_Float16)x1[e]; }
#pragma unroll
        for (int mi = 0; mi < 4; ++mi) {
            half8 a = *(const half8*)(wb + mi * 16 * FEAT + k);
            acc[mi] = __builtin_amdgcn_mfma_f32_16x16x32_f16(a, b, acc[mi], 0, 0, 0);
        }
    }

    if (kh == 1) {
#pragma unroll
        for (int mi = 0; mi < 4; ++mi)
#pragma unroll
            for (int r = 0; r < 4; ++r)
                cmb[ns][mi * 16 + g * 4 + r][l15] = acc[mi][r];
    }
    __syncthreads();
    if (kh == 0) {
        const int cc = ns * 2 + (l15 >> 3);
        const int e  = l15 & 7;
        float ps = 0.f, pn = 0.f;
#pragma unroll
        for (int mi = 0; mi < 4; ++mi) {
#pragma unroll
            for (int r = 0; r < 4; ++r) {
                int d = mi * 16 + g * 4 + r;
                float v = acc[mi][r] + cmb[ns][d][l15];
                Vt[((size_t)h * NT + bx) * 4096 + cc * 512 + d * 8 + e] = (_Float16)v;
                ps += v * a_self[h * DH + d];
                pn += v * a_neigh[h * DH + d];
            }
        }
        ps += __shfl_xor(ps, 16); ps += __shfl_xor(ps, 32);
        pn += __shfl_xor(pn, 16); pn += __shfl_xor(pn, 32);
        if (g == 0) {
            int n = n0 + l15;
            e_self[h * NODES + n] = ps;
            u_tab[h * NODES + n]  = (_Float16)__expf(pn);
            v_tab[h * NODES + n]  = (_Float16)__expf(0.2f * pn);
        }
        float mx = pn;
        mx = fmaxf(mx, __shfl_xor(mx, 1));
        mx = fmaxf(mx, __shfl_xor(mx, 2));
        mx = fmaxf(mx, __shfl_xor(mx, 4));
        mx = fmaxf(mx, __shfl_xor(mx, 8));
        if (lane == 0) atomicMax(enmax_u + h, fenc(mx));
    }
}

// ---------------- attn ----------------
// grid 1024 (128 i-tiles x 8 heads), 256 thr = 4 waves: rh = w&1 (16 rows),
// jq = w>>1 (2048 j in 32 steps of 64). Vlds[jq][buf][4096] f16 (32 KB),
// aliased as f32 reduction buffer after the loop.
__global__ __launch_bounds__(256, 4) void attn_kernel(
    const uint64_t* __restrict__ Abits2, const _Float16* __restrict__ Vt,
    const float* __restrict__ e_self, const _Float16* __restrict__ u_tab,
    const _Float16* __restrict__ v_tab, const uint32_t* __restrict__ enmax_u,
    const float* __restrict__ bias, float* __restrict__ out) {
    __shared__ __align__(16) _Float16 Vlds[2][2][4096];   // [jq][buf], 32 KB
    float* redf = (float*)&Vlds[0][0][0];                  // alias, used after loop

    const int tid  = threadIdx.x;
    const int w    = tid >> 6;
    const int lane = tid & 63;
    const int l15  = lane & 15;
    const int g    = lane >> 4;
    const int g8   = g * 8;
    const int rh   = w & 1;
    const int jq   = w >> 1;
    const int h    = blockIdx.x & 7;
    const int itile = blockIdx.x >> 3;
    const int i0   = itile * 32;

    const float em = fdec(enmax_u[h]);
    const float es = e_self[h * NODES + i0 + rh * 16 + l15];
    const float t0 = es + em;
    const float M  = fmaxf(t0, 0.2f * t0);
    const _Float16 c1 = (_Float16)__expf(es - M);
    const _Float16 c2 = (_Float16)__expf(0.2f * es - M);
    const half2v c1h = half2v{c1, c1};
    const half2v c2h = half2v{c2, c2};

    const _Float16* ub  = u_tab + h * NODES + jq * 2048 + g8;
    const _Float16* vb  = v_tab + h * NODES + jq * 2048 + g8;
    // bits: [itile][wc][row&31]; this wave reads rows rh*16+l15, wc = jq*32+s
    const uint64_t* ab2 = Abits2 + (size_t)itile * 2048 + (jq * 32) * 32 + rh * 16 + l15;
    const _Float16* vtb = Vt + ((size_t)h * NT + jq * 32) * 4096;

#define STAGE(s_, buf_) do {                                        \
        const _Float16* vs_ = vtb + (size_t)(s_) * 4096;            \
        _Float16* vd_ = &Vlds[jq][buf_][0];                         \
        _Pragma("unroll")                                           \
        for (int p_ = 0; p_ < 4; ++p_) {                            \
            const int c_ = rh * 256 + p_ * 64 + lane;               \
            gll16(vs_ + c_ * 8, vd_ + c_ * 8);                      \
        }                                                           \
    } while (0)

    f32x4 acc[4] = {};
    f32x4 asum = {};
    half8 ones;
#pragma unroll
    for (int e = 0; e < 8; ++e) ones[e] = (_Float16)1.0f;

    // prologue: stage tile 0 + scalar prefetch for s=0
    STAGE(0, 0);                               // 4 gll16 in flight
    uint64_t wb_c = ab2[0];                    // +1
    half8 uf_c[2], vf_c[2];                    // +4
#pragma unroll
    for (int kk = 0; kk < 2; ++kk) {
        uf_c[kk] = *(const half8*)(ub + kk * 32);
        vf_c[kk] = *(const half8*)(vb + kk * 32);
    }
    asm volatile("s_waitcnt vmcnt(5)" ::: "memory");   // gll16 landed; scalars in flight
    __builtin_amdgcn_sched_barrier(0);
    __builtin_amdgcn_s_barrier();
    __builtin_amdgcn_sched_barrier(0);

#pragma unroll 2
    for (int s = 0; s < 32; ++s) {
        const int buf = s & 1;
        // prefetch for s+1 (tail iters read into adjacent ws buffers: harmless)
        STAGE(s + 1, buf ^ 1);                 // 4 gll16
        uint64_t wb_n = ab2[(size_t)(s + 1) * 32];
        half8 uf_n[2], vf_n[2];
#pragma unroll
        for (int kk = 0; kk < 2; ++kk) {
            uf_n[kk] = *(const half8*)(ub + (s + 1) * 64 + kk * 32);
            vf_n[kk] = *(const half8*)(vb + (s + 1) * 64 + kk * 32);
        }

        const _Float16* vl = &Vlds[jq][buf][0];
#pragma unroll
        for (int kk = 0; kk < 2; ++kk) {
            const uint32_t b0 = ((uint32_t)(wb_c >> (kk * 32)) >> g8) & 0xFFu;
            half8 paf;
#pragma unroll
            for (int q = 0; q < 4; ++q) {
                half2v u2 = half2v{uf_c[kk][2 * q], uf_c[kk][2 * q + 1]};
                half2v v2 = half2v{vf_c[kk][2 * q], vf_c[kk][2 * q + 1]};
                half2v p2 = __builtin_elementwise_max(u2 * c1h, v2 * c2h);
                uint32_t mlo = (uint32_t)((int32_t)(b0 << (31 - 2 * q)) >> 31);
                uint32_t mhi = (uint32_t)((int32_t)(b0 << (30 - 2 * q)) >> 31);
                uint32_t m = (mhi & 0xFFFF0000u) | (mlo & 0xFFFFu);
                p2 = __builtin_bit_cast(half2v, __builtin_bit_cast(uint32_t, p2) & m);
                paf[2 * q] = p2[0]; paf[2 * q + 1] = p2[1];
            }
            __builtin_amdgcn_s_setprio(1);
#pragma unroll
            for (int ni = 0; ni < 4; ++ni) {
                const half8 vfr = *(const half8*)(vl + (kk * 4 + g) * 512 + (ni * 16 + l15) * 8);
                acc[ni] = __builtin_amdgcn_mfma_f32_16x16x32_f16(paf, vfr, acc[ni], 0, 0, 0);
            }
            asum = __builtin_amdgcn_mfma_f32_16x16x32_f16(paf, ones, asum, 0, 0, 0);
            __builtin_amdgcn_s_setprio(0);
        }
        wb_c = wb_n;
#pragma unroll
        for (int kk = 0; kk < 2; ++kk) { uf_c[kk] = uf_n[kk]; vf_c[kk] = vf_n[kk]; }

        // counted wait: my 4 stage-loads for s+1 done; 5 scalar prefetches stay
        asm volatile("s_waitcnt vmcnt(5)" ::: "memory");
        __builtin_amdgcn_sched_barrier(0);
        __builtin_amdgcn_s_barrier();
        __builtin_amdgcn_sched_barrier(0);
    }

    // ---- jq combine in aliased LDS (all tile reads done at last barrier) ----
    if (jq == 1) {
#pragma unroll
        for (int ni = 0; ni < 4; ++ni)
#pragma unroll
            for (int r = 0; r < 4; ++r)
                redf[(rh * 16 + g * 4 + r) * 68 + ni * 16 + l15] = acc[ni][r];
        if (l15 == 0) {
#pragma unroll
            for (int r = 0; r < 4; ++r)
                redf[2176 + rh * 16 + g * 4 + r] = asum[r];
        }
    }
    __syncthreads();
    if (jq == 0) {
        float invr[4];
#pragma unroll
        for (int r = 0; r < 4; ++r)
            invr[r] = 1.0f / (asum[r] + redf[2176 + rh * 16 + g * 4 + r]);
#pragma unroll
        for (int ni = 0; ni < 4; ++ni) {
            float bb = bias[h * DH + ni * 16 + l15];
#pragma unroll
            for (int r = 0; r < 4; ++r) {
                float v = (acc[ni][r] + redf[(rh * 16 + g * 4 + r) * 68 + ni * 16 + l15]) * invr[r] + bb;
                out[(size_t)(i0 + rh * 16 + g * 4 + r) * (HEADS * DH) + h * DH + ni * 16 + l15] =
                    fmaxf(v, 0.f);
            }
        }
    }
#undef STAGE
}

extern "C" void kernel_launch(void* const* d_in, const int* in_sizes, int n_in,
                              void* d_out, int out_size, void* d_ws, size_t ws_size,
                              hipStream_t stream) {
    const float* X       = (const float*)d_in[0];
    const float* A       = (const float*)d_in[1];
    const float* W       = (const float*)d_in[2];
    const float* b       = (const float*)d_in[3];
    const float* a_self  = (const float*)d_in[4];
    const float* a_neigh = (const float*)d_in[5];
    float* out = (float*)d_out;

    char* ws = (char*)d_ws;
    size_t off = 0;
    uint64_t* Abits2 = (uint64_t*)(ws + off); off += (size_t)128 * 2048 * 8;          // 2 MB
    _Float16* Xh     = (_Float16*)(ws + off); off += (size_t)NODES * FEAT * 2;        // 4 MB (spill pad)
    _Float16* WT     = (_Float16*)(ws + off); off += (size_t)HEADS * DH * FEAT * 2;   // 512 KB
    _Float16* Vt     = (_Float16*)(ws + off); off += (size_t)HEADS * DH * NODES * 2;  // 4 MB
    float* e_self    = (float*)(ws + off);    off += (size_t)HEADS * NODES * 4;       // 128 KB
    _Float16* u_tab  = (_Float16*)(ws + off); off += (size_t)HEADS * NODES * 2;       // 64 KB
    _Float16* v_tab  = (_Float16*)(ws + off); off += (size_t)HEADS * NODES * 2;       // 64 KB
    uint32_t* enmax_u = (uint32_t*)(ws + off); off += 64;
    (void)Xh;

    prep_kernel<<<PACK_BLOCKS + WT_BLOCKS, 256, 0, stream>>>(A, W, Abits2, WT, enmax_u);
    feats_kernel<<<dim3(NODES / 64, HEADS), 512, 0, stream>>>(
        X, WT, a_self, a_neigh, Vt, e_self, u_tab, v_tab, enmax_u);
    attn_kernel<<<(NODES / 32) * HEADS, 256, 0, stream>>>(
        Abits2, Vt, e_self, u_tab, v_tab, enmax_u, b, out);
}

// Round 14
// 99.007 us; speedup vs baseline: 1.1975x; 1.1975x over previous
//
#include <hip/hip_runtime.h>
#include <hip/hip_fp16.h>
#include <stdint.h>

// GAT: N=4096, F=512, H=8, D=64.
// score(h,i,j) = leaky(es_i + en_j); exp(leaky-M) = max(c1*u, c2*v) with
//   u=exp(en), v=exp(0.2*en), c1=exp(es-M), c2=exp(0.2*es-M); mask = AND with
//   byte-mask A (0xFF/0x00, fragment-ordered); fixed per-row M => no softmax
//   state, j-partials additive.
//
// attn: block = 32 rows x 1 head = 4 waves (2 rh x 2 jq), grid 1024, 4 blk/CU.
// Per step each jq stages a 64-j V tile via linear global_load_lds (Vt
// pre-tiled [cc][d][8]), double-buffered, 1 __syncthreads/step (r12 structure).
// Mask: 1 dwordx4/lane/step; bytes -> f16 masks via v_perm_b32 (1 inst/pair).

#define NODES 4096
#define FEAT  512
#define HEADS 8
#define DH    64
#define NT    (NODES / 64)

using half2v = __attribute__((ext_vector_type(2))) _Float16;
using half8  = __attribute__((ext_vector_type(8))) _Float16;
using f32x4  = __attribute__((ext_vector_type(4))) float;
using u32x4  = __attribute__((ext_vector_type(4))) uint32_t;

#if defined(__has_builtin)
#if __has_builtin(__builtin_amdgcn_perm)
#define HAS_PERM 1
#endif
#endif

__device__ __forceinline__ void gll16(const void* g, void* l) {
    __builtin_amdgcn_global_load_lds(
        (const __attribute__((address_space(1))) uint32_t*)g,
        (__attribute__((address_space(3))) uint32_t*)l, 16, 0, 0);
}

__device__ __forceinline__ uint32_t fenc(float f) {
    uint32_t u = __float_as_uint(f);
    return (u >> 31) ? ~u : (u | 0x80000000u);
}
__device__ __forceinline__ float fdec(uint32_t e) {
    uint32_t u = (e >> 31) ? (e & 0x7FFFFFFFu) : ~e;
    return __uint_as_float(u);
}

// expand 2 mask bytes (byte idx 2q, 2q+1 of reg r) into a 32-bit f16-pair mask
template <int Q>
__device__ __forceinline__ uint32_t mexpand(uint32_t r) {
#ifdef HAS_PERM
    const uint32_t sel = (Q & 1) ? 0x03030202u : 0x01010000u;
    return __builtin_amdgcn_perm(r, r, sel);
#else
    const int sh = (Q & 1) ? 8 : 24;
    uint32_t lo = (uint32_t)(((int32_t)(r << sh)) >> 31) & 0xFFFFu;
    uint32_t hi = (uint32_t)(((int32_t)(r << (sh - 8))) >> 31) & 0xFFFF0000u;
    return lo | hi;
#endif
}

// ---------------- prep: A->byte-mask (fragment order) | X->f16 | W->WT ----------------
// Amask[itile 0..127][wc 0..63][rh 0..1][lane 0..63][16 B]:
//   byte e<8:  A[itile*32+rh*16+(lane&15)][wc*64 +      (lane>>4)*8 + e]
//   byte e>=8: A[ same row              ][wc*64 + 32 + (lane>>4)*8 + e-8]
#define PACK_BLOCKS 4096                       // 4 waves/block, 16384 wave-tasks
#define CAST_BLOCKS (NODES * FEAT / 4 / 256)   // 2048
#define WT_BLOCKS   (HEADS * 8)                // 64

__global__ __launch_bounds__(256) void prep_kernel(
    const float* __restrict__ A, const float* __restrict__ X, const float* __restrict__ W,
    uint8_t* __restrict__ Amask, _Float16* __restrict__ Xh, _Float16* __restrict__ WT,
    uint32_t* __restrict__ enmax_u) {
    __shared__ float t[64][65];
    const int bx = blockIdx.x;
    if (bx < PACK_BLOCKS) {
        if (bx == 0 && threadIdx.x < 16) enmax_u[threadIdx.x] = 0;
        const int w    = threadIdx.x >> 6;
        const int lane = threadIdx.x & 63;
        const int vidx = bx * 4 + w;            // = (itile*64 + wc)*2 + rh
        const int itile = vidx >> 7;
        const int wc   = (vidx >> 1) & 63;
        const int rh   = vidx & 1;
        const int row  = itile * 32 + rh * 16 + (lane & 15);
        const int colb = wc * 64 + (lane >> 4) * 8;
        const float* ap = A + (size_t)row * NODES + colb;
        f32x4 a0 = *(const f32x4*)(ap);
        f32x4 a1 = *(const f32x4*)(ap + 4);
        f32x4 a2 = *(const f32x4*)(ap + 32);
        f32x4 a3 = *(const f32x4*)(ap + 36);
        u32x4 o;
        o[0] = ((a0[0] != 0.f) ? 0xFFu : 0u) | ((a0[1] != 0.f) ? 0xFF00u : 0u) |
               ((a0[2] != 0.f) ? 0xFF0000u : 0u) | ((a0[3] != 0.f) ? 0xFF000000u : 0u);
        o[1] = ((a1[0] != 0.f) ? 0xFFu : 0u) | ((a1[1] != 0.f) ? 0xFF00u : 0u) |
               ((a1[2] != 0.f) ? 0xFF0000u : 0u) | ((a1[3] != 0.f) ? 0xFF000000u : 0u);
        o[2] = ((a2[0] != 0.f) ? 0xFFu : 0u) | ((a2[1] != 0.f) ? 0xFF00u : 0u) |
               ((a2[2] != 0.f) ? 0xFF0000u : 0u) | ((a2[3] != 0.f) ? 0xFF000000u : 0u);
        o[3] = ((a3[0] != 0.f) ? 0xFFu : 0u) | ((a3[1] != 0.f) ? 0xFF00u : 0u) |
               ((a3[2] != 0.f) ? 0xFF0000u : 0u) | ((a3[3] != 0.f) ? 0xFF000000u : 0u);
        *(u32x4*)(Amask + ((size_t)vidx * 64 + lane) * 16) = o;
        return;
    }
    if (bx < PACK_BLOCKS + CAST_BLOCKS) {
        int i = ((bx - PACK_BLOCKS) * 256 + threadIdx.x) * 4;
        f32x4 x = *(const f32x4*)(X + i);
        *(half2v*)(Xh + i)     = half2v{(_Float16)x[0], (_Float16)x[1]};
        *(half2v*)(Xh + i + 2) = half2v{(_Float16)x[2], (_Float16)x[3]};
        return;
    }
    // W[h][f][d] -> WT[h][d][f] via LDS tile
    const int b2 = bx - PACK_BLOCKS - CAST_BLOCKS;
    const int h  = b2 >> 3;
    const int ft = b2 & 7;
    const int r  = threadIdx.x >> 6;
    const int c  = threadIdx.x & 63;
#pragma unroll
    for (int r0 = 0; r0 < 64; r0 += 4)
        t[r0 + r][c] = W[((size_t)h * FEAT + ft * 64 + r0 + r) * DH + c];
    __syncthreads();
#pragma unroll
    for (int r0 = 0; r0 < 64; r0 += 4)
        WT[((size_t)h * DH + r0 + r) * FEAT + ft * 64 + c] = (_Float16)t[c][r0 + r];
}

// ---------------- feats: grid (64 n-tiles, 8 heads), 4 waves, 64 MFMA/wave ----------------
// Vt written PRE-TILED: per (h, jt) tile of 4096 f16 as [cc 0..7][d 0..63][e 0..7],
// j = jt*64 + cc*8 + e  -> attn staging is a pure linear coalesced copy.
__global__ __launch_bounds__(256) void feats_kernel(
    const _Float16* __restrict__ Xh, const _Float16* __restrict__ WT,
    const float* __restrict__ a_self, const float* __restrict__ a_neigh,
    _Float16* __restrict__ Vt, float* __restrict__ e_self,
    _Float16* __restrict__ u_tab, _Float16* __restrict__ v_tab,
    uint32_t* __restrict__ enmax_u) {
    const int h    = blockIdx.y;
    const int bx   = blockIdx.x;
    const int tid  = threadIdx.x;
    const int w    = tid >> 6;
    const int lane = tid & 63;
    const int l15  = lane & 15;
    const int g    = lane >> 4;
    const int n0   = bx * 64 + w * 16;

    f32x4 acc[4] = {};
    const _Float16* xb = Xh + (n0 + l15) * FEAT + g * 8;
    const _Float16* wb = WT + (h * DH + l15) * FEAT + g * 8;

#pragma unroll
    for (int kk = 0; kk < FEAT / 32; ++kk) {
        half8 b = *(const half8*)(xb + kk * 32);
#pragma unroll
        for (int mi = 0; mi < 4; ++mi) {
            half8 a = *(const half8*)(wb + mi * 16 * FEAT + kk * 32);
            acc[mi] = __builtin_amdgcn_mfma_f32_16x16x32_f16(a, b, acc[mi], 0, 0, 0);
        }
    }

    const int cc = w * 2 + (l15 >> 3);     // j-chunk within tile
    const int e  = l15 & 7;
    float ps = 0.f, pn = 0.f;
#pragma unroll
    for (int mi = 0; mi < 4; ++mi) {
#pragma unroll
        for (int r = 0; r < 4; ++r) {
            int d = mi * 16 + g * 4 + r;
            float v = acc[mi][r];
            Vt[((size_t)h * NT + bx) * 4096 + cc * 512 + d * 8 + e] = (_Float16)v;
            ps += v * a_self[h * DH + d];
            pn += v * a_neigh[h * DH + d];
        }
    }
    ps += __shfl_xor(ps, 16); ps += __shfl_xor(ps, 32);
    pn += __shfl_xor(pn, 16); pn += __shfl_xor(pn, 32);
    if (g == 0) {
        int n = n0 + l15;
        e_self[h * NODES + n] = ps;
        u_tab[h * NODES + n]  = (_Float16)__expf(pn);
        v_tab[h * NODES + n]  = (_Float16)__expf(0.2f * pn);
    }
    float mx = pn;
    mx = fmaxf(mx, __shfl_xor(mx, 1));
    mx = fmaxf(mx, __shfl_xor(mx, 2));
    mx = fmaxf(mx, __shfl_xor(mx, 4));
    mx = fmaxf(mx, __shfl_xor(mx, 8));
    if (lane == 0) atomicMax(enmax_u + h, fenc(mx));
}

// ---------------- attn ----------------
// grid 1024 (128 i-tiles x 8 heads), 256 thr = 4 waves: rh = w&1 (16 rows),
// jq = w>>1 (2048 j in 32 steps of 64). LDS Vlds[jq][buf][4096] f16 (32 KB),
// aliased as the f32 reduction buffer after the loop.
__global__ __launch_bounds__(256, 4) void attn_kernel(
    const uint8_t* __restrict__ Amask, const _Float16* __restrict__ Vt,
    const float* __restrict__ e_self, const _Float16* __restrict__ u_tab,
    const _Float16* __restrict__ v_tab, const uint32_t* __restrict__ enmax_u,
    const float* __restrict__ bias, float* __restrict__ out) {
    __shared__ __align__(16) _Float16 Vlds[2][2][4096];   // [jq][buf], 32 KB
    float* redf = (float*)&Vlds[0][0][0];                  // alias, used after loop

    const int tid  = threadIdx.x;
    const int w    = tid >> 6;
    const int lane = tid & 63;
    const int l15  = lane & 15;
    const int g    = lane >> 4;
    const int g8   = g * 8;
    const int rh   = w & 1;
    const int jq   = w >> 1;
    const int h    = blockIdx.x & 7;
    const int itile = blockIdx.x >> 3;
    const int i0   = itile * 32;

    const float em = fdec(enmax_u[h]);
    const float es = e_self[h * NODES + i0 + rh * 16 + l15];
    const float t0 = es + em;
    const float M  = fmaxf(t0, 0.2f * t0);
    const _Float16 c1 = (_Float16)__expf(es - M);
    const _Float16 c2 = (_Float16)__expf(0.2f * es - M);
    const half2v c1h = half2v{c1, c1};
    const half2v c2h = half2v{c2, c2};

    const _Float16* ub  = u_tab + h * NODES + jq * 2048 + g8;
    const _Float16* vb  = v_tab + h * NODES + jq * 2048 + g8;
    // mask: [itile][wc][rh][lane][16B], wc = jq*32 + s; stride per s = 2048 B
    const uint8_t* amb = Amask + ((((size_t)itile * 64 + jq * 32) * 2 + rh) * 64 + lane) * 16;
    const _Float16* vtb = Vt + ((size_t)h * NT + jq * 32) * 4096;

#define STAGE(s_, buf_) do {                                        \
        const _Float16* vs_ = vtb + (size_t)(s_) * 4096;            \
        _Float16* vd_ = &Vlds[jq][buf_][0];                         \
        _Pragma("unroll")                                           \
        for (int p_ = 0; p_ < 4; ++p_) {                            \
            const int c_ = rh * 256 + p_ * 64 + lane;               \
            gll16(vs_ + c_ * 8, vd_ + c_ * 8);                      \
        }                                                           \
    } while (0)

    f32x4 acc[4] = {};
    f32x4 asum = {};
    half8 ones;
#pragma unroll
    for (int e = 0; e < 8; ++e) ones[e] = (_Float16)1.0f;

    // prologue: stage tile 0 + scalar prefetch for s=0
    STAGE(0, 0);
    u32x4 mk_c = *(const u32x4*)(amb);
    half8 uf_c[2], vf_c[2];
#pragma unroll
    for (int kk = 0; kk < 2; ++kk) {
        uf_c[kk] = *(const half8*)(ub + kk * 32);
        vf_c[kk] = *(const half8*)(vb + kk * 32);
    }
    __syncthreads();

#pragma unroll 2
    for (int s = 0; s < 32; ++s) {
        const int buf = s & 1;
        // prefetch for s+1 (tail iters read into adjacent ws buffers: harmless)
        STAGE(s + 1, buf ^ 1);
        u32x4 mk_n = *(const u32x4*)(amb + (size_t)(s + 1) * 2048);
        half8 uf_n[2], vf_n[2];
#pragma unroll
        for (int kk = 0; kk < 2; ++kk) {
            uf_n[kk] = *(const half8*)(ub + (s + 1) * 64 + kk * 32);
            vf_n[kk] = *(const half8*)(vb + (s + 1) * 64 + kk * 32);
        }

        const _Float16* vl = &Vlds[jq][buf][0];
#pragma unroll
        for (int kk = 0; kk < 2; ++kk) {
            half8 paf;
#pragma unroll
            for (int q = 0; q < 4; ++q) {
                half2v u2 = half2v{uf_c[kk][2 * q], uf_c[kk][2 * q + 1]};
                half2v v2 = half2v{vf_c[kk][2 * q], vf_c[kk][2 * q + 1]};
                half2v p2 = __builtin_elementwise_max(u2 * c1h, v2 * c2h);
                const uint32_t r = mk_c[kk * 2 + (q >> 1)];
                const uint32_t m = (q & 1) ? mexpand<1>(r) : mexpand<0>(r);
                p2 = __builtin_bit_cast(half2v, __builtin_bit_cast(uint32_t, p2) & m);
                paf[2 * q] = p2[0]; paf[2 * q + 1] = p2[1];
            }
            __builtin_amdgcn_s_setprio(1);
#pragma unroll
            for (int ni = 0; ni < 4; ++ni) {
                const half8 vfr = *(const half8*)(vl + (kk * 4 + g) * 512 + (ni * 16 + l15) * 8);
                acc[ni] = __builtin_amdgcn_mfma_f32_16x16x32_f16(paf, vfr, acc[ni], 0, 0, 0);
            }
            asum = __builtin_amdgcn_mfma_f32_16x16x32_f16(paf, ones, asum, 0, 0, 0);
            __builtin_amdgcn_s_setprio(0);
        }
        mk_c = mk_n;
#pragma unroll
        for (int kk = 0; kk < 2; ++kk) { uf_c[kk] = uf_n[kk]; vf_c[kk] = vf_n[kk]; }
        __syncthreads();
    }

    // ---- jq combine in aliased LDS (tile reads all done at last barrier) ----
    if (jq == 1) {
#pragma unroll
        for (int ni = 0; ni < 4; ++ni)
#pragma unroll
            for (int r = 0; r < 4; ++r)
                redf[(rh * 16 + g * 4 + r) * 68 + ni * 16 + l15] = acc[ni][r];
        if (l15 == 0) {
#pragma unroll
            for (int r = 0; r < 4; ++r)
                redf[2176 + rh * 16 + g * 4 + r] = asum[r];
        }
    }
    __syncthreads();
    if (jq == 0) {
        float invr[4];
#pragma unroll
        for (int r = 0; r < 4; ++r)
            invr[r] = 1.0f / (asum[r] + redf[2176 + rh * 16 + g * 4 + r]);
#pragma unroll
        for (int ni = 0; ni < 4; ++ni) {
            float bb = bias[h * DH + ni * 16 + l15];
#pragma unroll
            for (int r = 0; r < 4; ++r) {
                float v = (acc[ni][r] + redf[(rh * 16 + g * 4 + r) * 68 + ni * 16 + l15]) * invr[r] + bb;
                out[(size_t)(i0 + rh * 16 + g * 4 + r) * (HEADS * DH) + h * DH + ni * 16 + l15] =
                    fmaxf(v, 0.f);
            }
        }
    }
#undef STAGE
}

extern "C" void kernel_launch(void* const* d_in, const int* in_sizes, int n_in,
                              void* d_out, int out_size, void* d_ws, size_t ws_size,
                              hipStream_t stream) {
    const float* X       = (const float*)d_in[0];
    const float* A       = (const float*)d_in[1];
    const float* W       = (const float*)d_in[2];
    const float* b       = (const float*)d_in[3];
    const float* a_self  = (const float*)d_in[4];
    const float* a_neigh = (const float*)d_in[5];
    float* out = (float*)d_out;

    char* ws = (char*)d_ws;
    size_t off = 0;
    uint8_t* Amask   = (uint8_t*)(ws + off);  off += (size_t)NODES * NODES + 8192;   // 16.8 MB (+tail pad)
    _Float16* Xh     = (_Float16*)(ws + off); off += (size_t)NODES * FEAT * 2;        // 4 MB
    _Float16* WT     = (_Float16*)(ws + off); off += (size_t)HEADS * DH * FEAT * 2;   // 512 KB
    _Float16* Vt     = (_Float16*)(ws + off); off += (size_t)HEADS * DH * NODES * 2;  // 4 MB
    float* e_self    = (float*)(ws + off);    off += (size_t)HEADS * NODES * 4;       // 128 KB
    _Float16* u_tab  = (_Float16*)(ws + off); off += (size_t)HEADS * NODES * 2;       // 64 KB
    _Float16* v_tab  = (_Float16*)(ws + off); off += (size_t)HEADS * NODES * 2;       // 64 KB
    uint32_t* enmax_u = (uint32_t*)(ws + off); off += 8192;                            // + tail pad

    prep_kernel<<<PACK_BLOCKS + CAST_BLOCKS + WT_BLOCKS, 256, 0, stream>>>(
        A, X, W, Amask, Xh, WT, enmax_u);
    feats_kernel<<<dim3(NODES / 64, HEADS), 256, 0, stream>>>(
        Xh, WT, a_self, a_neigh, Vt, e_self, u_tab, v_tab, enmax_u);
    attn_kernel<<<(NODES / 32) * HEADS, 256, 0, stream>>>(
        Amask, Vt, e_self, u_tab, v_tab, enmax_u, b, out);
}